// Round 1
// baseline (11357.860 us; speedup 1.0000x reference)
//
#include <hip/hip_runtime.h>
#include <cstdint>
#include <cstddef>

typedef __attribute__((ext_vector_type(8))) short short8;
typedef __attribute__((ext_vector_type(4))) float floatx4;

constexpr int kSeq = 512;
constexpr int kBatch = 256;
constexpr int kIn = 15;
constexpr int kH = 512;
constexpr int kG = 4 * kH;  // 2048 gate columns, order i,f,g,o

__device__ __forceinline__ unsigned short f2bf(float f) {
    union { float f; unsigned u; } v; v.f = f;
    unsigned u = v.u;
    return (unsigned short)((u + 0x7fffu + ((u >> 16) & 1u)) >> 16);
}

__device__ __forceinline__ float sigm(float x) { return 1.0f / (1.0f + __expf(-x)); }
__device__ __forceinline__ float tanh_(float x) { return 1.0f - 2.0f / (1.0f + __expf(2.0f * x)); }

// plain f32 -> bf16
__global__ void k_conv(const float* __restrict__ src, unsigned short* __restrict__ dst, int n) {
    int i = blockIdx.x * blockDim.x + threadIdx.x;
    if (i < n) dst[i] = f2bf(src[i]);
}

// rows of kIn f32 -> rows of 32 bf16, zero padded
__global__ void k_conv_pad(const float* __restrict__ src, unsigned short* __restrict__ dst, int rows) {
    int i = blockIdx.x * blockDim.x + threadIdx.x;
    if (i >= rows * 32) return;
    int r = i >> 5, k = i & 31;
    dst[i] = (k < kIn) ? f2bf(src[r * kIn + k]) : (unsigned short)0;
}

// One pipeline phase: layer-1 step t (blocks 0..127) + layer-2 step t-1 (blocks 128..255).
// Block tile: 64 batch rows x 16 hidden units x 4 gates. 4 waves, each wave a 16-row strip.
__global__ __launch_bounds__(256) void k_phase(
    int t,
    const unsigned short* __restrict__ whh1,  // (2048,512) bf16
    const unsigned short* __restrict__ wih1,  // (2048,32) bf16, cols >=15 zero
    const unsigned short* __restrict__ wih2,  // (2048,512) bf16
    const unsigned short* __restrict__ whh2,  // (2048,512) bf16
    const unsigned short* __restrict__ xb,    // (512,256,32) bf16, cols >=15 zero
    const float* __restrict__ bih1, const float* __restrict__ bhh1,
    const float* __restrict__ bih2, const float* __restrict__ bhh2,
    unsigned short* __restrict__ h1b0, unsigned short* __restrict__ h1b1,
    unsigned short* __restrict__ h2b0, unsigned short* __restrict__ h2b1,
    float* __restrict__ c1, float* __restrict__ c2,
    float* __restrict__ h2f)
{
    const int bid = blockIdx.x;
    const bool is2 = bid >= 128;
    if (!is2 && t >= kSeq) return;   // no layer-1 work in last phase
    if (is2 && t < 1) return;        // no layer-2 work in first phase
    const int lb = bid & 127;
    const int mt = lb >> 5;          // 0..3 : 64-row batch tile
    const int j0 = (lb & 31) << 4;   // hidden-unit base 0..496
    const int wave = (int)(threadIdx.x >> 6);
    const int lane = (int)(threadIdx.x & 63);
    const int lcol = lane & 15;
    const int quad = lane >> 4;
    const int m0 = mt * 64 + wave * 16;   // this wave's 16-row strip
    const int s = is2 ? (t - 1) : t;      // LSTM step this block computes

    // accumulators: one 16x16 tile per gate; init with biases (same for all rows)
    floatx4 acc[4];
#pragma unroll
    for (int g = 0; g < 4; ++g) {
        int n = g * kH + j0 + lcol;
        float b = is2 ? (bih2[n] + bhh2[n]) : (bih1[n] + bhh1[n]);
        acc[g] = (floatx4){b, b, b, b};
    }

    const int arow = m0 + lcol;  // A-operand row for this lane
    const int koff = quad * 8;   // A/B k-offset for this lane

    if (!is2) {
        // h1prev = h1[s-1], stored in buf[(s-1)&1]
        const unsigned short* hprev = (s & 1) ? h1b0 : h1b1;
        const unsigned short* ap = hprev + (size_t)arow * kH + koff;
#pragma unroll
        for (int kk = 0; kk < kH / 32; ++kk) {
            short8 a = *reinterpret_cast<const short8*>(ap + kk * 32);
#pragma unroll
            for (int g = 0; g < 4; ++g) {
                int n = g * kH + j0 + lcol;
                short8 b = *reinterpret_cast<const short8*>(whh1 + (size_t)n * kH + kk * 32 + koff);
                acc[g] = __builtin_amdgcn_mfma_f32_16x16x32_bf16(a, b, acc[g], 0, 0, 0);
            }
        }
        {   // x_t contribution (padded K=32)
            short8 a = *reinterpret_cast<const short8*>(xb + ((size_t)s * kBatch + arow) * 32 + koff);
#pragma unroll
            for (int g = 0; g < 4; ++g) {
                int n = g * kH + j0 + lcol;
                short8 b = *reinterpret_cast<const short8*>(wih1 + n * 32 + koff);
                acc[g] = __builtin_amdgcn_mfma_f32_16x16x32_bf16(a, b, acc[g], 0, 0, 0);
            }
        }
    } else {
        // layer-2 step s: inputs h1[s] (buf[s&1]) and h2[s-1] (buf[(s-1)&1])
        const unsigned short* h1s = (s & 1) ? h1b1 : h1b0;
        const unsigned short* h2p = (s & 1) ? h2b0 : h2b1;
        const unsigned short* ap1 = h1s + (size_t)arow * kH + koff;
        const unsigned short* ap2 = h2p + (size_t)arow * kH + koff;
#pragma unroll
        for (int kk = 0; kk < kH / 32; ++kk) {
            short8 a = *reinterpret_cast<const short8*>(ap1 + kk * 32);
#pragma unroll
            for (int g = 0; g < 4; ++g) {
                int n = g * kH + j0 + lcol;
                short8 b = *reinterpret_cast<const short8*>(wih2 + (size_t)n * kH + kk * 32 + koff);
                acc[g] = __builtin_amdgcn_mfma_f32_16x16x32_bf16(a, b, acc[g], 0, 0, 0);
            }
        }
#pragma unroll
        for (int kk = 0; kk < kH / 32; ++kk) {
            short8 a = *reinterpret_cast<const short8*>(ap2 + kk * 32);
#pragma unroll
            for (int g = 0; g < 4; ++g) {
                int n = g * kH + j0 + lcol;
                short8 b = *reinterpret_cast<const short8*>(whh2 + (size_t)n * kH + kk * 32 + koff);
                acc[g] = __builtin_amdgcn_mfma_f32_16x16x32_bf16(a, b, acc[g], 0, 0, 0);
            }
        }
    }

    // epilogue: activations + state update.
    // C/D layout: row m = m0 + quad*4 + r, col j = j0 + lcol. Lane has i,f,g,o for same (m,j).
    unsigned short* hw = !is2 ? ((s & 1) ? h1b1 : h1b0)
                              : ((s & 1) ? h2b1 : h2b0);
    float* cc = !is2 ? c1 : c2;
    const int j = j0 + lcol;
#pragma unroll
    for (int r = 0; r < 4; ++r) {
        int m = m0 + quad * 4 + r;
        float gi = acc[0][r];
        float gf = acc[1][r];
        float gg = acc[2][r];
        float go = acc[3][r];
        float cold = cc[(size_t)m * kH + j];
        float cn = sigm(gf) * cold + sigm(gi) * tanh_(gg);
        float hn = sigm(go) * tanh_(cn);
        cc[(size_t)m * kH + j] = cn;
        hw[(size_t)m * kH + j] = f2bf(hn);
        if (is2 && s == kSeq - 1) h2f[(size_t)m * kH + j] = hn;
    }
}

// MLP head: out[m] = 2*(relu(relu(h2[m])@fc1_w.T + fc1_b)@fc_w.T + fc_b)
__global__ __launch_bounds__(64) void k_head(
    const float* __restrict__ h2f, const float* __restrict__ fc1w,
    const float* __restrict__ fc1b, const float* __restrict__ fcw,
    const float* __restrict__ fcb, float* __restrict__ out)
{
    int m = blockIdx.x;
    int j = threadIdx.x;  // 0..63 : FC_HID unit
    const float* hr = h2f + (size_t)m * kH;
    const float* wr = fc1w + (size_t)j * kH;
    float sacc = 0.f;
    for (int k = 0; k < kH; ++k) sacc += fmaxf(hr[k], 0.f) * wr[k];
    float rv = fmaxf(sacc + fc1b[j], 0.f) * fcw[j];
#pragma unroll
    for (int off = 32; off >= 1; off >>= 1) rv += __shfl_down(rv, off);
    if (j == 0) out[m] = 2.0f * (rv + fcb[0]);
}

extern "C" void kernel_launch(void* const* d_in, const int* in_sizes, int n_in,
                              void* d_out, int out_size, void* d_ws, size_t ws_size,
                              hipStream_t stream) {
    const float* x    = (const float*)d_in[0];
    const float* Wih1 = (const float*)d_in[1];
    const float* Whh1 = (const float*)d_in[2];
    const float* bih1 = (const float*)d_in[3];
    const float* bhh1 = (const float*)d_in[4];
    const float* Wih2 = (const float*)d_in[5];
    const float* Whh2 = (const float*)d_in[6];
    const float* bih2 = (const float*)d_in[7];
    const float* bhh2 = (const float*)d_in[8];
    const float* fc1w = (const float*)d_in[9];
    const float* fc1b = (const float*)d_in[10];
    const float* fcw  = (const float*)d_in[11];
    const float* fcb  = (const float*)d_in[12];
    float* out = (float*)d_out;

    char* p = (char*)d_ws;
    auto take = [&](size_t bytes) -> char* {
        char* r = p;
        p += (bytes + 255) & ~(size_t)255;
        return r;
    };
    unsigned short* whh1b = (unsigned short*)take((size_t)kG * kH * 2);
    unsigned short* wih2b = (unsigned short*)take((size_t)kG * kH * 2);
    unsigned short* whh2b = (unsigned short*)take((size_t)kG * kH * 2);
    unsigned short* wih1b = (unsigned short*)take((size_t)kG * 32 * 2);
    unsigned short* xb    = (unsigned short*)take((size_t)kSeq * kBatch * 32 * 2);
    char* state = p;
    unsigned short* h1b0 = (unsigned short*)take((size_t)kBatch * kH * 2);
    unsigned short* h1b1 = (unsigned short*)take((size_t)kBatch * kH * 2);
    unsigned short* h2b0 = (unsigned short*)take((size_t)kBatch * kH * 2);
    unsigned short* h2b1 = (unsigned short*)take((size_t)kBatch * kH * 2);
    float* c1 = (float*)take((size_t)kBatch * kH * 4);
    float* c2 = (float*)take((size_t)kBatch * kH * 4);
    size_t state_bytes = (size_t)((char*)c2 + (size_t)kBatch * kH * 4 - state);
    float* h2f = (float*)take((size_t)kBatch * kH * 4);

    // zero h/c state (ws is poisoned 0xAA before every launch)
    hipMemsetAsync(state, 0, state_bytes, stream);

    // weight/input conversion to bf16 (re-done every call; no persistent state)
    int n = kG * kH;
    k_conv<<<(n + 255) / 256, 256, 0, stream>>>(Whh1, whh1b, n);
    k_conv<<<(n + 255) / 256, 256, 0, stream>>>(Wih2, wih2b, n);
    k_conv<<<(n + 255) / 256, 256, 0, stream>>>(Whh2, whh2b, n);
    k_conv_pad<<<(kG * 32 + 255) / 256, 256, 0, stream>>>(Wih1, wih1b, kG);
    k_conv_pad<<<(kSeq * kBatch * 32 + 255) / 256, 256, 0, stream>>>(x, xb, kSeq * kBatch);

    // 513 pipeline phases
    for (int t = 0; t <= kSeq; ++t) {
        k_phase<<<256, 256, 0, stream>>>(t, whh1b, wih1b, wih2b, whh2b, xb,
                                         bih1, bhh1, bih2, bhh2,
                                         h1b0, h1b1, h2b0, h2b1, c1, c2, h2f);
    }

    k_head<<<kBatch, 64, 0, stream>>>(h2f, fc1w, fc1b, fcw, fcb, out);
}